// Round 18
// baseline (348.510 us; speedup 1.0000x reference)
//
#include <hip/hip_runtime.h>
#include <hip/hip_fp16.h>
#include <math.h>

// ---------------------------------------------------------------------------
// HAN forward: N=30000/type, E=480000/edge-type, F_IN=16, HID=64, HEADS=2,
// D=32, L=2. Round-17 structure (337us, fp16 gather payload). NEW: bin branch
// de-latency-chained -- BIN_CHUNK 1024 (2x blocks), batched d/s loads, d
// values cached in registers across passes (no re-load in scatter).
// ---------------------------------------------------------------------------

#define GEMM_GRID 1024  // per side
#define ENCB 1024       // encproj blocks per side inside phase1
#define KRED_GRID 256   // per side
#define FINALB 2048
#define BUCKET_SHIFT 6
#define BUCKET_NODES 64
#define BUCKET_CAP 1536
#define BIN_CHUNK 1024  // 4 edges/thread, fully batched

__device__ __forceinline__ float4 ld4(const float* __restrict__ p, int idx4)
{
    return ((const float4*)p)[idx4];
}

__device__ __forceinline__ float halfred(float v)
{
#pragma unroll
    for (int off = 16; off; off >>= 1) v += __shfl_xor(v, off);
    return v;
}

__device__ __forceinline__ float2 sem_attn(const float* __restrict__ kacc,
                                           const float* __restrict__ qsem,
                                           float inv_n, int lane)
{
    float qc = qsem[lane];
    float v0 = qc * kacc[lane] * inv_n;
    float v1 = qc * kacc[64 + lane] * inv_n;
#pragma unroll
    for (int off = 32; off; off >>= 1) {
        v0 += __shfl_xor(v0, off);
        v1 += __shfl_xor(v1, off);
    }
    float m = fmaxf(v0, v1);
    float e0 = __expf(v0 - m), e1 = __expf(v1 - m);
    float inv = 1.f / (e0 + e1);
    return {e0 * inv, e1 * inv};
}

// ---------------------------------------------------------------------------
struct ProjSide {
    const float* x0; const float* x1;
    const float* kacc; const float* qsem; float inv_n;
    const float* W; const float* b; __half* p;
    const float* a0v; float* o0; const float* a1v; float* o1;
    const float* a2v; float* o2; const float* a3v; float* o3;
};

__global__ __launch_bounds__(256, 4) void proj2_kernel(ProjSide sa, ProjSide sb, int n)
{
    const ProjSide S = blockIdx.y ? sb : sa;
    __shared__ __align__(16) float xs[16][64];
    int tid = threadIdx.x, lane = tid & 63, wid = tid >> 6;
    float Wreg[64];
#pragma unroll
    for (int k = 0; k < 64; k++) Wreg[k] = S.W[k * 64 + lane];
    float bc = S.b[lane];
    float a0c = S.o0 ? S.a0v[lane] : 0.f;
    float a1c = S.o1 ? S.a1v[lane] : 0.f;
    float a2c = S.o2 ? S.a2v[lane] : 0.f;
    float a3c = S.o3 ? S.a3v[lane] : 0.f;
    float ca0 = 0.f, ca1 = 0.f;
    if (S.x1) {
        float2 at = sem_attn(S.kacc, S.qsem, S.inv_n, lane);
        ca0 = at.x; ca1 = at.y;
    }
    int qn = tid >> 4, qq = tid & 15;
    for (int base = blockIdx.x * 16; base < n; base += gridDim.x * 16) {
        __syncthreads();
        int node = base + qn;
        if (node < n) {
            float4 xq;
            if (S.x1) {
                float4 u = ld4(S.x0, node * 16 + qq), v = ld4(S.x1, node * 16 + qq);
                xq.x = ca0 * u.x + ca1 * v.x; xq.y = ca0 * u.y + ca1 * v.y;
                xq.z = ca0 * u.z + ca1 * v.z; xq.w = ca0 * u.w + ca1 * v.w;
            } else {
                xq = ld4(S.x0, node * 16 + qq);
            }
            *(float4*)&xs[qn][qq * 4] = xq;
        }
        __syncthreads();
#pragma unroll
        for (int nd = 0; nd < 4; nd++) {
            int nc = base + wid * 4 + nd;
            if (nc >= n) break;
            float acc = bc;
#pragma unroll
            for (int k4 = 0; k4 < 16; k4++) {
                float4 xv = *(const float4*)&xs[wid * 4 + nd][k4 * 4];
                acc = fmaf(xv.x, Wreg[4 * k4 + 0], acc);
                acc = fmaf(xv.y, Wreg[4 * k4 + 1], acc);
                acc = fmaf(xv.z, Wreg[4 * k4 + 2], acc);
                acc = fmaf(xv.w, Wreg[4 * k4 + 3], acc);
            }
            S.p[(size_t)nc * 64 + lane] = __float2half(acc);
            int h = lane >> 5;
            if (S.o0) { float v = halfred(acc * a0c); if ((lane & 31) == 0) S.o0[nc * 2 + h] = v; }
            if (S.o1) { float v = halfred(acc * a1c); if ((lane & 31) == 0) S.o1[nc * 2 + h] = v; }
            if (S.o2) { float v = halfred(acc * a2c); if ((lane & 31) == 0) S.o2[nc * 2 + h] = v; }
            if (S.o3) { float v = halfred(acc * a3c); if ((lane & 31) == 0) S.o3[nc * 2 + h] = v; }
        }
    }
}

// ---------------------------------------------------------------------------
struct EncSide {
    const float* x; const float* We; const float* be;
    const float* W; const float* b; __half* p;
    const float* a0v; float* o0; const float* a1v; float* o1;
    const float* a2v; float* o2; const float* a3v; float* o3;
};

union Phase1Smem {
    struct { float xs[16][16]; float es[16][64]; } enc;    // 5.25 KB
    struct { int cnt[2][512]; int rbase[2][512]; } bin;    // 8 KB
};

__device__ __forceinline__ void encproj_body(const EncSide& S, Phase1Smem* sm,
                                             int bx, int nblk, int n)
{
    float (*xs)[16] = sm->enc.xs;
    float (*es)[64] = sm->enc.es;
    int tid = threadIdx.x, lane = tid & 63, wid = tid >> 6;
    float Ereg[16];
#pragma unroll
    for (int k = 0; k < 16; k++) Ereg[k] = S.We[k * 64 + lane];
    float Wreg[64];
#pragma unroll
    for (int k = 0; k < 64; k++) Wreg[k] = S.W[k * 64 + lane];
    float ebc = S.be[lane], bc = S.b[lane];
    float a0c = S.o0 ? S.a0v[lane] : 0.f;
    float a1c = S.o1 ? S.a1v[lane] : 0.f;
    float a2c = S.o2 ? S.a2v[lane] : 0.f;
    float a3c = S.o3 ? S.a3v[lane] : 0.f;
    for (int base = bx * 16; base < n; base += nblk * 16) {
        __syncthreads();
        if (tid < 64) {
            int nn = tid >> 2, q = tid & 3;
            int node = base + nn;
            if (node < n) *(float4*)&xs[nn][q * 4] = ld4(S.x, node * 4 + q);
        }
        __syncthreads();
#pragma unroll
        for (int nd = 0; nd < 4; nd++) {
            int nc = base + wid * 4 + nd;
            if (nc >= n) break;
            float a = ebc;
#pragma unroll
            for (int k4 = 0; k4 < 4; k4++) {
                float4 xv = *(const float4*)&xs[wid * 4 + nd][k4 * 4];
                a = fmaf(xv.x, Ereg[4 * k4 + 0], a);
                a = fmaf(xv.y, Ereg[4 * k4 + 1], a);
                a = fmaf(xv.z, Ereg[4 * k4 + 2], a);
                a = fmaf(xv.w, Ereg[4 * k4 + 3], a);
            }
            es[wid * 4 + nd][lane] = fmaxf(a, 0.f);
        }
        __syncthreads();
#pragma unroll
        for (int nd = 0; nd < 4; nd++) {
            int nc = base + wid * 4 + nd;
            if (nc >= n) break;
            float acc = bc;
#pragma unroll
            for (int k4 = 0; k4 < 16; k4++) {
                float4 xv = *(const float4*)&es[wid * 4 + nd][k4 * 4];
                acc = fmaf(xv.x, Wreg[4 * k4 + 0], acc);
                acc = fmaf(xv.y, Wreg[4 * k4 + 1], acc);
                acc = fmaf(xv.z, Wreg[4 * k4 + 2], acc);
                acc = fmaf(xv.w, Wreg[4 * k4 + 3], acc);
            }
            S.p[(size_t)nc * 64 + lane] = __float2half(acc);
            int h = lane >> 5;
            if (S.o0) { float v = halfred(acc * a0c); if ((lane & 31) == 0) S.o0[nc * 2 + h] = v; }
            if (S.o1) { float v = halfred(acc * a1c); if ((lane & 31) == 0) S.o1[nc * 2 + h] = v; }
            if (S.o2) { float v = halfred(acc * a2c); if ((lane & 31) == 0) S.o2[nc * 2 + h] = v; }
            if (S.o3) { float v = halfred(acc * a3c); if ((lane & 31) == 0) S.o3[nc * 2 + h] = v; }
        }
    }
}

// batched loads, d cached in registers across passes (4 edges/thread)
__device__ __forceinline__ void bin_body(const int* __restrict__ s, const int* __restrict__ d,
                                         int* __restrict__ cursor, int* __restrict__ binned,
                                         Phase1Smem* sm, int ty, int cx, int e, int nb)
{
    int (*cnt)[512] = sm->bin.cnt;
    int (*rbase)[512] = sm->bin.rbase;
    int tid = threadIdx.x, w2 = tid >> 7;
    for (int i = tid; i < 1024; i += 256) cnt[0][i] = 0;
    __syncthreads();
    int beg = cx * BIN_CHUNK;
    int end = beg + BIN_CHUNK; if (end > e) end = e;
    int i0 = beg + tid;
    int dv[4]; bool va[4];
#pragma unroll
    for (int k = 0; k < 4; k++) {
        int i = i0 + k * 256;
        va[k] = i < end;
        dv[k] = va[k] ? d[i] : 0;
    }
#pragma unroll
    for (int k = 0; k < 4; k++)
        if (va[k]) atomicAdd(&cnt[w2][dv[k] >> BUCKET_SHIFT], 1);
    __syncthreads();
    for (int i = tid; i < nb; i += 256) {
        int c0 = cnt[0][i], c1 = cnt[1][i];
        int tot = c0 + c1;
        int rb = tot ? atomicAdd(&cursor[ty * nb + i], tot) : 0;
        rbase[0][i] = rb;
        rbase[1][i] = rb + c0;
    }
    __syncthreads();
    for (int i = tid; i < 1024; i += 256) cnt[0][i] = 0;
    __syncthreads();
    int sv[4];
#pragma unroll
    for (int k = 0; k < 4; k++) {
        int i = i0 + k * 256;
        sv[k] = va[k] ? s[i] : 0;
    }
    int* bb = binned + (size_t)ty * nb * BUCKET_CAP;
#pragma unroll
    for (int k = 0; k < 4; k++) {
        if (va[k]) {
            int b = dv[k] >> BUCKET_SHIFT;
            int slot = rbase[w2][b] + atomicAdd(&cnt[w2][b], 1);
            if (slot < BUCKET_CAP)
                bb[b * BUCKET_CAP + slot] = (sv[k] << BUCKET_SHIFT) | (dv[k] & (BUCKET_NODES - 1));
        }
    }
}

__global__ __launch_bounds__(256) void phase1_kernel(
    EncSide sa, EncSide sb, int n,
    const int* __restrict__ s0, const int* __restrict__ s1, const int* __restrict__ s2,
    const int* __restrict__ d0, const int* __restrict__ d1, const int* __restrict__ d2,
    int* __restrict__ cursor, int* __restrict__ binned, int e, int nb, int binb)
{
    __shared__ Phase1Smem sm;
    int bid = blockIdx.x;
    int nbin = 3 * binb;
    if (bid < nbin) {
        int ty = bid / binb, cx = bid % binb;
        const int* s = ty == 0 ? s0 : (ty == 1 ? s1 : s2);
        const int* d = ty == 0 ? d0 : (ty == 1 ? d1 : d2);
        bin_body(s, d, cursor, binned, &sm, ty, cx, e, nb);
    } else {
        int r = bid - nbin;
        encproj_body(r >= ENCB ? sb : sa, &sm, r & (ENCB - 1), ENCB, n);
    }
}

// ---------------------------------------------------------------------------
__global__ __launch_bounds__(256) void bucket_kernel(
    const int* __restrict__ cursor, const int* __restrict__ binned,
    int* __restrict__ rowptr, int* __restrict__ rowend, int* __restrict__ colsrc,
    int n, int nb, int e)
{
    int ty = blockIdx.y, b = blockIdx.x;
    __shared__ int stage[BUCKET_CAP];
    __shared__ int ncnt[64], nexcl[64], ncur[64];
    __shared__ int wpart[4];
    int tid = threadIdx.x, lane = tid & 63, wid = tid >> 6;
    int part = 0;
    for (int i = tid; i < b; i += 256) part += cursor[ty * nb + i];
#pragma unroll
    for (int off = 32; off; off >>= 1) part += __shfl_xor(part, off);
    if (lane == 0) wpart[wid] = part;
    int cnt = cursor[ty * nb + b]; if (cnt > BUCKET_CAP) cnt = BUCKET_CAP;
    const int* bb = binned + ((size_t)ty * nb + b) * BUCKET_CAP;
    if (tid < 64) ncnt[tid] = 0;
    __syncthreads();
    int base = wpart[0] + wpart[1] + wpart[2] + wpart[3];
    for (int i = tid; i < cnt; i += 256) {
        int v = bb[i];
        stage[i] = v;
        atomicAdd(&ncnt[v & (BUCKET_NODES - 1)], 1);
    }
    __syncthreads();
    if (tid < 64) {
        int v = ncnt[tid];
        int incl = v;
#pragma unroll
        for (int off = 1; off < 64; off <<= 1) {
            int u = __shfl_up(incl, off);
            if (tid >= off) incl += u;
        }
        int excl = incl - v;
        nexcl[tid] = excl;
        ncur[tid] = 0;
        int node = (b << BUCKET_SHIFT) + tid;
        if (node < n) {
            rowptr[(size_t)ty * n + node] = base + excl;
            rowend[(size_t)ty * n + node] = base + excl + v;
        }
    }
    __syncthreads();
    int* cs = colsrc + (size_t)ty * e;
    for (int i = tid; i < cnt; i += 256) {
        int v = stage[i];
        int dl = v & (BUCKET_NODES - 1);
        int pos = nexcl[dl] + atomicAdd(&ncur[dl], 1);
        cs[base + pos] = v >> BUCKET_SHIFT;
    }
}

// ---------------------------------------------------------------------------
// Fused edge-softmax + aggregation; xsrc is fp16 (8B/lane gathers).
// ---------------------------------------------------------------------------
struct AggSide {
    const int* rp; const int* re; const int* cs;
    const __half* xsrc; const float* as; const float* ad;
    float* out;
};

__device__ __forceinline__ float4 ldh4(const __half* __restrict__ p, int idx4)
{
    __half2 h01 = ((const __half2*)p)[idx4 * 2];
    __half2 h23 = ((const __half2*)p)[idx4 * 2 + 1];
    float2 f01 = __half22float2(h01);
    float2 f23 = __half22float2(h23);
    return {f01.x, f01.y, f23.x, f23.y};
}

__global__ __launch_bounds__(256, 8) void agg3_kernel(AggSide A0, AggSide A1, AggSide A2, int n)
{
    const AggSide A = blockIdx.y == 0 ? A0 : (blockIdx.y == 1 ? A1 : A2);
    __shared__ int ebs[4][32];
    __shared__ float ebw[4][2][32];
    int tid = threadIdx.x;
    int lane = tid & 63, wid = tid >> 6;
    int node = blockIdx.x * 4 + wid;
    if (node >= n) return;
    int l32 = lane & 31;
    int hh = lane >> 5;
    int g = lane >> 4;
    int q = lane & 15;
    int hq = q >> 3;
    int beg = A.rp[node], end = A.re[node];
    float ad = A.ad[node * 2 + hh];
    float den = 0.f;
    float4 acc = {0.f, 0.f, 0.f, 0.f};
    int* es = ebs[wid];
    float* ew = ebw[wid][0];
    for (int c = beg; c < end; c += 32) {
        int cnt = end - c; if (cnt > 32) cnt = 32;
        int sl = A.cs[c + (l32 < cnt ? l32 : 0)];
        float w = 0.f;
        if (l32 < cnt) {
            float a = A.as[sl * 2 + hh] + ad;
            a = (a > 0.f) ? a : 0.2f * a;
            w = __expf(a);
        }
        den += w;
        if (lane < 32) es[l32] = sl;
        ew[hh * 32 + l32] = w;
        int iters = (cnt + 3) >> 2;
        int it = 0;
        for (; it + 4 <= iters; it += 4) {
            int e0 = it * 4 + g;
            int s0 = es[e0], s1 = es[e0 + 4], s2 = es[e0 + 8], s3 = es[e0 + 12];
            float w0 = ew[hq * 32 + e0],     w1 = ew[hq * 32 + e0 + 4];
            float w2 = ew[hq * 32 + e0 + 8], w3 = ew[hq * 32 + e0 + 12];
            float4 x0 = ldh4(A.xsrc, s0 * 16 + q);
            float4 x1 = ldh4(A.xsrc, s1 * 16 + q);
            float4 x2 = ldh4(A.xsrc, s2 * 16 + q);
            float4 x3 = ldh4(A.xsrc, s3 * 16 + q);
            acc.x = fmaf(w0, x0.x, acc.x); acc.y = fmaf(w0, x0.y, acc.y);
            acc.z = fmaf(w0, x0.z, acc.z); acc.w = fmaf(w0, x0.w, acc.w);
            acc.x = fmaf(w1, x1.x, acc.x); acc.y = fmaf(w1, x1.y, acc.y);
            acc.z = fmaf(w1, x1.z, acc.z); acc.w = fmaf(w1, x1.w, acc.w);
            acc.x = fmaf(w2, x2.x, acc.x); acc.y = fmaf(w2, x2.y, acc.y);
            acc.z = fmaf(w2, x2.z, acc.z); acc.w = fmaf(w2, x2.w, acc.w);
            acc.x = fmaf(w3, x3.x, acc.x); acc.y = fmaf(w3, x3.y, acc.y);
            acc.z = fmaf(w3, x3.z, acc.z); acc.w = fmaf(w3, x3.w, acc.w);
        }
        for (; it < iters; it++) {
            int e0 = it * 4 + g;
            int s0 = es[e0];
            float w0 = ew[hq * 32 + e0];
            float4 x0 = ldh4(A.xsrc, s0 * 16 + q);
            acc.x = fmaf(w0, x0.x, acc.x); acc.y = fmaf(w0, x0.y, acc.y);
            acc.z = fmaf(w0, x0.z, acc.z); acc.w = fmaf(w0, x0.w, acc.w);
        }
    }
    acc.x += __shfl_xor(acc.x, 16);
    acc.y += __shfl_xor(acc.y, 16);
    acc.z += __shfl_xor(acc.z, 16);
    acc.w += __shfl_xor(acc.w, 16);
    acc.x += __shfl_xor(acc.x, 32);
    acc.y += __shfl_xor(acc.y, 32);
    acc.z += __shfl_xor(acc.z, 32);
    acc.w += __shfl_xor(acc.w, 32);
    float dtot = halfred(den);
    float dq = __shfl(dtot, (q >= 8) ? 32 : 0);
    if (g == 0) {
        float r = 1.f / (dq + 1e-16f);
        float4 o;
        o.x = fmaxf(acc.x * r, 0.f);
        o.y = fmaxf(acc.y * r, 0.f);
        o.z = fmaxf(acc.z * r, 0.f);
        o.w = fmaxf(acc.w * r, 0.f);
        *(float4*)&A.out[node * 64 + q * 4] = o;
    }
}

// ---------------------------------------------------------------------------
__global__ __launch_bounds__(256, 4) void kred2_kernel(
    const float* __restrict__ xin0, const float* __restrict__ xin1,
    const float* __restrict__ kw, const float* __restrict__ kb,
    float* __restrict__ kacc0, float* __restrict__ kacc1, int n)
{
    const float* xin = blockIdx.y ? xin1 : xin0;
    float* kacc = blockIdx.y ? kacc1 : kacc0;
    __shared__ __align__(16) float xs[16][64];
    __shared__ float red[256];
    int tid = threadIdx.x, lane = tid & 63, wid = tid >> 6;
    float Wreg[64];
#pragma unroll
    for (int k = 0; k < 64; k++) Wreg[k] = kw[k * 64 + lane];
    float bc = kb[lane];
    int qn = tid >> 4, qq = tid & 15;
    float kl = 0.f;
    for (int base = blockIdx.x * 16; base < n; base += gridDim.x * 16) {
        __syncthreads();
        int node = base + qn;
        if (node < n) *(float4*)&xs[qn][qq * 4] = ld4(xin, node * 16 + qq);
        __syncthreads();
#pragma unroll
        for (int nd = 0; nd < 4; nd++) {
            int nc = base + wid * 4 + nd;
            if (nc >= n) break;
            float acc = bc;
#pragma unroll
            for (int k4 = 0; k4 < 16; k4++) {
                float4 xv = *(const float4*)&xs[wid * 4 + nd][k4 * 4];
                acc = fmaf(xv.x, Wreg[4 * k4 + 0], acc);
                acc = fmaf(xv.y, Wreg[4 * k4 + 1], acc);
                acc = fmaf(xv.z, Wreg[4 * k4 + 2], acc);
                acc = fmaf(xv.w, Wreg[4 * k4 + 3], acc);
            }
            kl += tanhf(acc);
        }
    }
    red[tid] = kl;
    __syncthreads();
    if (wid == 0) {
        float s = red[lane] + red[64 + lane] + red[128 + lane] + red[192 + lane];
        atomicAdd(&kacc[lane], s);
    }
}

// ---------------------------------------------------------------------------
__global__ __launch_bounds__(256, 4) void final_kernel(
    const float* __restrict__ t0, const float* __restrict__ t1,
    const float* __restrict__ kacc, const float* __restrict__ qsem, float inv_n,
    const float* __restrict__ xm,
    const float* __restrict__ w0, const float* __restrict__ b0,
    const float* __restrict__ w1, const float* __restrict__ b1,
    const float* __restrict__ wv,
    float* __restrict__ action, float* __restrict__ vsum, int n)
{
    __shared__ __align__(16) float xs[16][64];
    __shared__ __align__(16) float hs[4][4][68];
    __shared__ float W1s[1024];
    __shared__ float red[256];
    int tid = threadIdx.x, lane = tid & 63, wid = tid >> 6;
    int qn = tid >> 4, qq = tid & 15;
    float W0reg[64];
#pragma unroll
    for (int k = 0; k < 64; k++) W0reg[k] = w0[k * 64 + lane];
    float b0c = b0[lane], b1c = b1[lane & 15];
    float2 at = sem_attn(kacc, qsem, inv_n, lane);
    float ca0 = at.x, ca1 = at.y;
    float4 wvq = ld4(wv, qq);
    for (int i = tid; i < 1024; i += 256) W1s[i] = w1[i];
    float vloc = 0.f;
    int n2 = 2 * n;
    for (int base = blockIdx.x * 16; base < n2; base += gridDim.x * 16) {
        __syncthreads();
        int node = base + qn;
        if (node < n2) {
            float4 xq;
            if (node < n) {
                float4 u = ld4(t0, node * 16 + qq), v = ld4(t1, node * 16 + qq);
                xq.x = ca0 * u.x + ca1 * v.x; xq.y = ca0 * u.y + ca1 * v.y;
                xq.z = ca0 * u.z + ca1 * v.z; xq.w = ca0 * u.w + ca1 * v.w;
            } else {
                xq = ld4(xm, (node - n) * 16 + qq);
            }
            *(float4*)&xs[qn][qq * 4] = xq;
            vloc += xq.x * wvq.x + xq.y * wvq.y + xq.z * wvq.z + xq.w * wvq.w;
        }
        __syncthreads();
#pragma unroll
        for (int nd = 0; nd < 4; nd++) {
            int nc = base + wid * 4 + nd;
            if (nc >= n2) break;
            float acc = b0c;
#pragma unroll
            for (int k4 = 0; k4 < 16; k4++) {
                float4 xv = *(const float4*)&xs[wid * 4 + nd][k4 * 4];
                acc = fmaf(xv.x, W0reg[4 * k4 + 0], acc);
                acc = fmaf(xv.y, W0reg[4 * k4 + 1], acc);
                acc = fmaf(xv.z, W0reg[4 * k4 + 2], acc);
                acc = fmaf(xv.w, W0reg[4 * k4 + 3], acc);
            }
            hs[wid][nd][lane] = acc;
        }
        __syncthreads();
        int nd2 = lane >> 4, c2 = lane & 15;
        int nc2 = base + wid * 4 + nd2;
        if (nc2 < n2) {
            float acc2 = b1c;
#pragma unroll
            for (int k4 = 0; k4 < 16; k4++) {
                float4 hv = *(const float4*)&hs[wid][nd2][k4 * 4];
                acc2 = fmaf(hv.x, W1s[(4 * k4 + 0) * 16 + c2], acc2);
                acc2 = fmaf(hv.y, W1s[(4 * k4 + 1) * 16 + c2], acc2);
                acc2 = fmaf(hv.z, W1s[(4 * k4 + 2) * 16 + c2], acc2);
                acc2 = fmaf(hv.w, W1s[(4 * k4 + 3) * 16 + c2], acc2);
            }
            action[(size_t)nc2 * 16 + c2] = tanhf(acc2);
        }
    }
    red[tid] = vloc;
    __syncthreads();
    for (int s = 128; s; s >>= 1) {
        if (tid < s) red[tid] += red[tid + s];
        __syncthreads();
    }
    if (tid == 0) atomicAdd(vsum, red[0]);
}

__global__ void value_finish_kernel(const float* __restrict__ vsum,
                                    const float* __restrict__ vb,
                                    float* __restrict__ out, int twoN)
{
    if (threadIdx.x == 0 && blockIdx.x == 0)
        out[0] = vsum[0] / (float)twoN + vb[0];
}

extern "C" void kernel_launch(void* const* d_in, const int* in_sizes, int n_in,
                              void* d_out, int out_size, void* d_ws, size_t ws_size,
                              hipStream_t stream)
{
    const int N = in_sizes[0] / 16;
    const int E = in_sizes[2] / 2;
    const int NB = (N + BUCKET_NODES - 1) / BUCKET_NODES;

    auto f = [&](int i) { return (const float*)d_in[i]; };
    const float* x_job = f(0);
    const float* x_mac = f(1);
    const int* ei_jm = (const int*)d_in[2];
    const int* ei_mj = (const int*)d_in[3];
    const int* ei_jj = (const int*)d_in[4];
    const float* enc_wj = f(5);
    const float* enc_bj = f(6);
    const float* enc_wm = f(7);
    const float* enc_bm = f(8);
    const float* proj_w = f(9);
    const float* proj_b = f(10);
    const float* att_src = f(11);
    const float* att_dst = f(12);
    const float* klin_w = f(13);
    const float* klin_b = f(14);
    const float* q_sem = f(15);
    const float* lin0_w = f(16);
    const float* lin0_b = f(17);
    const float* lout_w = f(18);
    const float* lout_b = f(19);
    const float* linv_w = f(20);
    const float* linv_b = f(21);

    float* action = (float*)d_out;
    float* value_out = action + (size_t)2 * N * 16;

    char* base = (char*)d_ws;
    size_t off = 0;
    auto alloc = [&](size_t bytes) -> void* {
        void* p = base + off;
        off += (bytes + 255) & ~(size_t)255;
        return p;
    };
    int* cursor3 = (int*)alloc((size_t)3 * NB * 4);
    float* kacc = (float*)alloc(256 * 4);
    float* vsum = (float*)alloc(4);
    size_t zero_bytes = off;

    int* rowptr3 = (int*)alloc((size_t)3 * N * 4);
    int* rowend3 = (int*)alloc((size_t)3 * N * 4);
    int* colsrc3 = (int*)alloc((size_t)3 * E * 4);
    int* binned3 = (int*)alloc((size_t)3 * NB * BUCKET_CAP * 4);
    __half* pj = (__half*)alloc((size_t)N * 64 * 2);
    __half* pm = (__half*)alloc((size_t)N * 64 * 2);
    float* out_jm0 = (float*)alloc((size_t)N * 64 * 4);
    float* out_jm1 = (float*)alloc((size_t)N * 64 * 4);
    float* out_mj = (float*)alloc((size_t)N * 64 * 4);
    float* out_jj = (float*)alloc((size_t)N * 64 * 4);
    float* as_jm = (float*)alloc((size_t)N * 2 * 4);
    float* ad_jm = (float*)alloc((size_t)N * 2 * 4);
    float* as_mj = (float*)alloc((size_t)N * 2 * 4);
    float* ad_mj = (float*)alloc((size_t)N * 2 * 4);
    float* as_jj = (float*)alloc((size_t)N * 2 * 4);
    float* ad_jj = (float*)alloc((size_t)N * 2 * 4);

    hipMemsetAsync(d_ws, 0, zero_bytes, stream);

    dim3 blk(256);

    const int* rp0 = rowptr3;
    const int* rp1 = rowptr3 + N;
    const int* rp2 = rowptr3 + 2 * N;
    const int* re0 = rowend3;
    const int* re1 = rowend3 + N;
    const int* re2 = rowend3 + 2 * N;
    const int* cs0 = colsrc3;
    const int* cs1 = colsrc3 + E;
    const int* cs2 = colsrc3 + 2 * E;

    int ab = (N + 3) / 4;
    int binb = (E + BIN_CHUNK - 1) / BIN_CHUNK;
    float* out_jm_l[2] = {out_jm0, out_jm1};
    float inv_n = 1.f / (float)N;

    for (int l = 0; l < 2; l++) {
        const float* pwj = proj_w + (size_t)(l * 2 + 0) * 4096;
        const float* pwm = proj_w + (size_t)(l * 2 + 1) * 4096;
        const float* pbj = proj_b + (l * 2 + 0) * 64;
        const float* pbm = proj_b + (l * 2 + 1) * 64;
        const float* as0 = att_src + (l * 3 + 0) * 64;
        const float* as1 = att_src + (l * 3 + 1) * 64;
        const float* as2 = att_src + (l * 3 + 2) * 64;
        const float* ad0 = att_dst + (l * 3 + 0) * 64;
        const float* ad1 = att_dst + (l * 3 + 1) * 64;
        const float* ad2 = att_dst + (l * 3 + 2) * 64;

        if (l == 0) {
            EncSide ja = {x_job, enc_wj, enc_bj, pwj, pbj, pj,
                          as0, as_jm, ad1, ad_mj, as2, as_jj, ad2, ad_jj};
            EncSide ma = {x_mac, enc_wm, enc_bm, pwm, pbm, pm,
                          ad0, ad_jm, as1, as_mj, nullptr, nullptr, nullptr, nullptr};
            phase1_kernel<<<3 * binb + 2 * ENCB, blk, 0, stream>>>(
                ja, ma, N, ei_jm, ei_mj, ei_jj, ei_jm + E, ei_mj + E, ei_jj + E,
                cursor3, binned3, E, NB, binb);
            bucket_kernel<<<dim3(NB, 3), blk, 0, stream>>>(
                cursor3, binned3, rowptr3, rowend3, colsrc3, N, NB, E);
        } else {
            ProjSide ja = {out_mj, out_jj, kacc, q_sem, inv_n, pwj, pbj, pj,
                           as0, as_jm, ad1, ad_mj, as2, as_jj, ad2, ad_jj};
            ProjSide ma = {out_jm0, nullptr, nullptr, nullptr, 0.f, pwm, pbm, pm,
                           ad0, ad_jm, as1, as_mj, nullptr, nullptr, nullptr, nullptr};
            proj2_kernel<<<dim3(GEMM_GRID, 2), blk, 0, stream>>>(ja, ma, N);
        }

        AggSide A0 = {rp0, re0, cs0, pj, as_jm, ad_jm, out_jm_l[l]};
        AggSide A1 = {rp1, re1, cs1, pm, as_mj, ad_mj, out_mj};
        AggSide A2 = {rp2, re2, cs2, pj, as_jj, ad_jj, out_jj};
        agg3_kernel<<<dim3(ab, 3), blk, 0, stream>>>(A0, A1, A2, N);

        const float* kw = klin_w + (size_t)l * 4096;
        const float* kb = klin_b + l * 64;
        float* k0 = kacc + l * 128;
        float* k1 = k0 + 64;
        kred2_kernel<<<dim3(KRED_GRID, 2), blk, 0, stream>>>(out_mj, out_jj, kw, kb, k0, k1, N);
    }

    final_kernel<<<FINALB, blk, 0, stream>>>(out_mj, out_jj,
                                             kacc + 128, q_sem + 64, inv_n,
                                             out_jm1,
                                             lin0_w, lin0_b, lout_w, lout_b, linv_w,
                                             action, vsum, N);
    value_finish_kernel<<<1, 64, 0, stream>>>(vsum, linv_b, value_out, 2 * N);
}

// Round 19
// 335.068 us; speedup vs baseline: 1.0401x; 1.0401x over previous
//
#include <hip/hip_runtime.h>
#include <hip/hip_fp16.h>
#include <math.h>

// ---------------------------------------------------------------------------
// HAN forward: N=30000/type, E=480000/edge-type, F_IN=16, HID=64, HEADS=2,
// D=32, L=2. BEST-KNOWN configuration (round 17, 336.7us):
//  - f32 compute; pj/pm gather payloads stored fp16 (halves agg3's random-
//    gather traffic, the dominant memory cost; absmax 1.9e-3 vs 5.4e-3 thr)
//  - CSR via two-level counting sort (BIN_CHUNK 2048 -- 1024 regressed:
//    per-block fixed LDS/cursor costs double and dominate)
//  - phase1 = encproj(2 sides)+bin(3 types) fused, LDS union, 2-way hist
//  - agg3: 32-edge chunks, exp-once per (edge,head), split LDS (sl,w) bufs,
//    4x-unrolled fp16x4 gathers, lane remap g/q, shfl_xor fold
//  - dense kernels: W register-resident, x via LDS-staged float4 broadcast,
//    grids sized for 8 blocks/CU (TLP hides the serial FMA chains)
//  - semantic softmax folded into proj2/final (T=1 group is identity)
// Known-bad (measured): per-block __threadfence done-counter (+20us);
// interleaved acc chains (VGPR 160 or spill); wave-uniform global broadcast
// loads (latency-serial); separate scatter w/ atomics (14x write amp).
// ---------------------------------------------------------------------------

#define GEMM_GRID 1024  // per side
#define ENCB 1024       // encproj blocks per side inside phase1
#define KRED_GRID 256   // per side
#define FINALB 2048
#define BUCKET_SHIFT 6
#define BUCKET_NODES 64
#define BUCKET_CAP 1536
#define BIN_CHUNK 2048

__device__ __forceinline__ float4 ld4(const float* __restrict__ p, int idx4)
{
    return ((const float4*)p)[idx4];
}

__device__ __forceinline__ float halfred(float v)
{
#pragma unroll
    for (int off = 16; off; off >>= 1) v += __shfl_xor(v, off);
    return v;
}

__device__ __forceinline__ float2 sem_attn(const float* __restrict__ kacc,
                                           const float* __restrict__ qsem,
                                           float inv_n, int lane)
{
    float qc = qsem[lane];
    float v0 = qc * kacc[lane] * inv_n;
    float v1 = qc * kacc[64 + lane] * inv_n;
#pragma unroll
    for (int off = 32; off; off >>= 1) {
        v0 += __shfl_xor(v0, off);
        v1 += __shfl_xor(v1, off);
    }
    float m = fmaxf(v0, v1);
    float e0 = __expf(v0 - m), e1 = __expf(v1 - m);
    float inv = 1.f / (e0 + e1);
    return {e0 * inv, e1 * inv};
}

// ---------------------------------------------------------------------------
struct ProjSide {
    const float* x0; const float* x1;
    const float* kacc; const float* qsem; float inv_n;
    const float* W; const float* b; __half* p;
    const float* a0v; float* o0; const float* a1v; float* o1;
    const float* a2v; float* o2; const float* a3v; float* o3;
};

__global__ __launch_bounds__(256, 4) void proj2_kernel(ProjSide sa, ProjSide sb, int n)
{
    const ProjSide S = blockIdx.y ? sb : sa;
    __shared__ __align__(16) float xs[16][64];
    int tid = threadIdx.x, lane = tid & 63, wid = tid >> 6;
    float Wreg[64];
#pragma unroll
    for (int k = 0; k < 64; k++) Wreg[k] = S.W[k * 64 + lane];
    float bc = S.b[lane];
    float a0c = S.o0 ? S.a0v[lane] : 0.f;
    float a1c = S.o1 ? S.a1v[lane] : 0.f;
    float a2c = S.o2 ? S.a2v[lane] : 0.f;
    float a3c = S.o3 ? S.a3v[lane] : 0.f;
    float ca0 = 0.f, ca1 = 0.f;
    if (S.x1) {
        float2 at = sem_attn(S.kacc, S.qsem, S.inv_n, lane);
        ca0 = at.x; ca1 = at.y;
    }
    int qn = tid >> 4, qq = tid & 15;
    for (int base = blockIdx.x * 16; base < n; base += gridDim.x * 16) {
        __syncthreads();
        int node = base + qn;
        if (node < n) {
            float4 xq;
            if (S.x1) {
                float4 u = ld4(S.x0, node * 16 + qq), v = ld4(S.x1, node * 16 + qq);
                xq.x = ca0 * u.x + ca1 * v.x; xq.y = ca0 * u.y + ca1 * v.y;
                xq.z = ca0 * u.z + ca1 * v.z; xq.w = ca0 * u.w + ca1 * v.w;
            } else {
                xq = ld4(S.x0, node * 16 + qq);
            }
            *(float4*)&xs[qn][qq * 4] = xq;
        }
        __syncthreads();
#pragma unroll
        for (int nd = 0; nd < 4; nd++) {
            int nc = base + wid * 4 + nd;
            if (nc >= n) break;
            float acc = bc;
#pragma unroll
            for (int k4 = 0; k4 < 16; k4++) {
                float4 xv = *(const float4*)&xs[wid * 4 + nd][k4 * 4];
                acc = fmaf(xv.x, Wreg[4 * k4 + 0], acc);
                acc = fmaf(xv.y, Wreg[4 * k4 + 1], acc);
                acc = fmaf(xv.z, Wreg[4 * k4 + 2], acc);
                acc = fmaf(xv.w, Wreg[4 * k4 + 3], acc);
            }
            S.p[(size_t)nc * 64 + lane] = __float2half(acc);
            int h = lane >> 5;
            if (S.o0) { float v = halfred(acc * a0c); if ((lane & 31) == 0) S.o0[nc * 2 + h] = v; }
            if (S.o1) { float v = halfred(acc * a1c); if ((lane & 31) == 0) S.o1[nc * 2 + h] = v; }
            if (S.o2) { float v = halfred(acc * a2c); if ((lane & 31) == 0) S.o2[nc * 2 + h] = v; }
            if (S.o3) { float v = halfred(acc * a3c); if ((lane & 31) == 0) S.o3[nc * 2 + h] = v; }
        }
    }
}

// ---------------------------------------------------------------------------
struct EncSide {
    const float* x; const float* We; const float* be;
    const float* W; const float* b; __half* p;
    const float* a0v; float* o0; const float* a1v; float* o1;
    const float* a2v; float* o2; const float* a3v; float* o3;
};

union Phase1Smem {
    struct { float xs[16][16]; float es[16][64]; } enc;    // 5.25 KB
    struct { int cnt[2][512]; int rbase[2][512]; } bin;    // 8 KB
};

__device__ __forceinline__ void encproj_body(const EncSide& S, Phase1Smem* sm,
                                             int bx, int nblk, int n)
{
    float (*xs)[16] = sm->enc.xs;
    float (*es)[64] = sm->enc.es;
    int tid = threadIdx.x, lane = tid & 63, wid = tid >> 6;
    float Ereg[16];
#pragma unroll
    for (int k = 0; k < 16; k++) Ereg[k] = S.We[k * 64 + lane];
    float Wreg[64];
#pragma unroll
    for (int k = 0; k < 64; k++) Wreg[k] = S.W[k * 64 + lane];
    float ebc = S.be[lane], bc = S.b[lane];
    float a0c = S.o0 ? S.a0v[lane] : 0.f;
    float a1c = S.o1 ? S.a1v[lane] : 0.f;
    float a2c = S.o2 ? S.a2v[lane] : 0.f;
    float a3c = S.o3 ? S.a3v[lane] : 0.f;
    for (int base = bx * 16; base < n; base += nblk * 16) {
        __syncthreads();
        if (tid < 64) {
            int nn = tid >> 2, q = tid & 3;
            int node = base + nn;
            if (node < n) *(float4*)&xs[nn][q * 4] = ld4(S.x, node * 4 + q);
        }
        __syncthreads();
#pragma unroll
        for (int nd = 0; nd < 4; nd++) {
            int nc = base + wid * 4 + nd;
            if (nc >= n) break;
            float a = ebc;
#pragma unroll
            for (int k4 = 0; k4 < 4; k4++) {
                float4 xv = *(const float4*)&xs[wid * 4 + nd][k4 * 4];
                a = fmaf(xv.x, Ereg[4 * k4 + 0], a);
                a = fmaf(xv.y, Ereg[4 * k4 + 1], a);
                a = fmaf(xv.z, Ereg[4 * k4 + 2], a);
                a = fmaf(xv.w, Ereg[4 * k4 + 3], a);
            }
            es[wid * 4 + nd][lane] = fmaxf(a, 0.f);
        }
        __syncthreads();
#pragma unroll
        for (int nd = 0; nd < 4; nd++) {
            int nc = base + wid * 4 + nd;
            if (nc >= n) break;
            float acc = bc;
#pragma unroll
            for (int k4 = 0; k4 < 16; k4++) {
                float4 xv = *(const float4*)&es[wid * 4 + nd][k4 * 4];
                acc = fmaf(xv.x, Wreg[4 * k4 + 0], acc);
                acc = fmaf(xv.y, Wreg[4 * k4 + 1], acc);
                acc = fmaf(xv.z, Wreg[4 * k4 + 2], acc);
                acc = fmaf(xv.w, Wreg[4 * k4 + 3], acc);
            }
            S.p[(size_t)nc * 64 + lane] = __float2half(acc);
            int h = lane >> 5;
            if (S.o0) { float v = halfred(acc * a0c); if ((lane & 31) == 0) S.o0[nc * 2 + h] = v; }
            if (S.o1) { float v = halfred(acc * a1c); if ((lane & 31) == 0) S.o1[nc * 2 + h] = v; }
            if (S.o2) { float v = halfred(acc * a2c); if ((lane & 31) == 0) S.o2[nc * 2 + h] = v; }
            if (S.o3) { float v = halfred(acc * a3c); if ((lane & 31) == 0) S.o3[nc * 2 + h] = v; }
        }
    }
}

__device__ __forceinline__ void bin_body(const int* __restrict__ s, const int* __restrict__ d,
                                         int* __restrict__ cursor, int* __restrict__ binned,
                                         Phase1Smem* sm, int ty, int cx, int e, int nb)
{
    int (*cnt)[512] = sm->bin.cnt;
    int (*rbase)[512] = sm->bin.rbase;
    int tid = threadIdx.x, w2 = tid >> 7;
    for (int i = tid; i < 1024; i += 256) cnt[0][i] = 0;
    __syncthreads();
    int beg = cx * BIN_CHUNK;
    int end = beg + BIN_CHUNK; if (end > e) end = e;
    for (int i = beg + tid; i < end; i += 256)
        atomicAdd(&cnt[w2][d[i] >> BUCKET_SHIFT], 1);
    __syncthreads();
    for (int i = tid; i < nb; i += 256) {
        int c0 = cnt[0][i], c1 = cnt[1][i];
        int tot = c0 + c1;
        int rb = tot ? atomicAdd(&cursor[ty * nb + i], tot) : 0;
        rbase[0][i] = rb;
        rbase[1][i] = rb + c0;
    }
    __syncthreads();
    for (int i = tid; i < 1024; i += 256) cnt[0][i] = 0;
    __syncthreads();
    int* bb = binned + (size_t)ty * nb * BUCKET_CAP;
    for (int i = beg + tid; i < end; i += 256) {
        int dv = d[i], b = dv >> BUCKET_SHIFT;
        int slot = rbase[w2][b] + atomicAdd(&cnt[w2][b], 1);
        if (slot < BUCKET_CAP)
            bb[b * BUCKET_CAP + slot] = (s[i] << BUCKET_SHIFT) | (dv & (BUCKET_NODES - 1));
    }
}

__global__ __launch_bounds__(256) void phase1_kernel(
    EncSide sa, EncSide sb, int n,
    const int* __restrict__ s0, const int* __restrict__ s1, const int* __restrict__ s2,
    const int* __restrict__ d0, const int* __restrict__ d1, const int* __restrict__ d2,
    int* __restrict__ cursor, int* __restrict__ binned, int e, int nb, int binb)
{
    __shared__ Phase1Smem sm;
    int bid = blockIdx.x;
    int nbin = 3 * binb;
    if (bid < nbin) {
        int ty = bid / binb, cx = bid % binb;
        const int* s = ty == 0 ? s0 : (ty == 1 ? s1 : s2);
        const int* d = ty == 0 ? d0 : (ty == 1 ? d1 : d2);
        bin_body(s, d, cursor, binned, &sm, ty, cx, e, nb);
    } else {
        int r = bid - nbin;
        encproj_body(r >= ENCB ? sb : sa, &sm, r & (ENCB - 1), ENCB, n);
    }
}

// ---------------------------------------------------------------------------
__global__ __launch_bounds__(256) void bucket_kernel(
    const int* __restrict__ cursor, const int* __restrict__ binned,
    int* __restrict__ rowptr, int* __restrict__ rowend, int* __restrict__ colsrc,
    int n, int nb, int e)
{
    int ty = blockIdx.y, b = blockIdx.x;
    __shared__ int stage[BUCKET_CAP];
    __shared__ int ncnt[64], nexcl[64], ncur[64];
    __shared__ int wpart[4];
    int tid = threadIdx.x, lane = tid & 63, wid = tid >> 6;
    int part = 0;
    for (int i = tid; i < b; i += 256) part += cursor[ty * nb + i];
#pragma unroll
    for (int off = 32; off; off >>= 1) part += __shfl_xor(part, off);
    if (lane == 0) wpart[wid] = part;
    int cnt = cursor[ty * nb + b]; if (cnt > BUCKET_CAP) cnt = BUCKET_CAP;
    const int* bb = binned + ((size_t)ty * nb + b) * BUCKET_CAP;
    if (tid < 64) ncnt[tid] = 0;
    __syncthreads();
    int base = wpart[0] + wpart[1] + wpart[2] + wpart[3];
    for (int i = tid; i < cnt; i += 256) {
        int v = bb[i];
        stage[i] = v;
        atomicAdd(&ncnt[v & (BUCKET_NODES - 1)], 1);
    }
    __syncthreads();
    if (tid < 64) {
        int v = ncnt[tid];
        int incl = v;
#pragma unroll
        for (int off = 1; off < 64; off <<= 1) {
            int u = __shfl_up(incl, off);
            if (tid >= off) incl += u;
        }
        int excl = incl - v;
        nexcl[tid] = excl;
        ncur[tid] = 0;
        int node = (b << BUCKET_SHIFT) + tid;
        if (node < n) {
            rowptr[(size_t)ty * n + node] = base + excl;
            rowend[(size_t)ty * n + node] = base + excl + v;
        }
    }
    __syncthreads();
    int* cs = colsrc + (size_t)ty * e;
    for (int i = tid; i < cnt; i += 256) {
        int v = stage[i];
        int dl = v & (BUCKET_NODES - 1);
        int pos = nexcl[dl] + atomicAdd(&ncur[dl], 1);
        cs[base + pos] = v >> BUCKET_SHIFT;
    }
}

// ---------------------------------------------------------------------------
// Fused edge-softmax + aggregation; xsrc is fp16 (8B/lane gathers).
// ---------------------------------------------------------------------------
struct AggSide {
    const int* rp; const int* re; const int* cs;
    const __half* xsrc; const float* as; const float* ad;
    float* out;
};

__device__ __forceinline__ float4 ldh4(const __half* __restrict__ p, int idx4)
{
    __half2 h01 = ((const __half2*)p)[idx4 * 2];
    __half2 h23 = ((const __half2*)p)[idx4 * 2 + 1];
    float2 f01 = __half22float2(h01);
    float2 f23 = __half22float2(h23);
    return {f01.x, f01.y, f23.x, f23.y};
}

__global__ __launch_bounds__(256, 8) void agg3_kernel(AggSide A0, AggSide A1, AggSide A2, int n)
{
    const AggSide A = blockIdx.y == 0 ? A0 : (blockIdx.y == 1 ? A1 : A2);
    __shared__ int ebs[4][32];
    __shared__ float ebw[4][2][32];
    int tid = threadIdx.x;
    int lane = tid & 63, wid = tid >> 6;
    int node = blockIdx.x * 4 + wid;
    if (node >= n) return;
    int l32 = lane & 31;
    int hh = lane >> 5;
    int g = lane >> 4;
    int q = lane & 15;
    int hq = q >> 3;
    int beg = A.rp[node], end = A.re[node];
    float ad = A.ad[node * 2 + hh];
    float den = 0.f;
    float4 acc = {0.f, 0.f, 0.f, 0.f};
    int* es = ebs[wid];
    float* ew = ebw[wid][0];
    for (int c = beg; c < end; c += 32) {
        int cnt = end - c; if (cnt > 32) cnt = 32;
        int sl = A.cs[c + (l32 < cnt ? l32 : 0)];
        float w = 0.f;
        if (l32 < cnt) {
            float a = A.as[sl * 2 + hh] + ad;
            a = (a > 0.f) ? a : 0.2f * a;
            w = __expf(a);
        }
        den += w;
        if (lane < 32) es[l32] = sl;
        ew[hh * 32 + l32] = w;
        int iters = (cnt + 3) >> 2;
        int it = 0;
        for (; it + 4 <= iters; it += 4) {
            int e0 = it * 4 + g;
            int s0 = es[e0], s1 = es[e0 + 4], s2 = es[e0 + 8], s3 = es[e0 + 12];
            float w0 = ew[hq * 32 + e0],     w1 = ew[hq * 32 + e0 + 4];
            float w2 = ew[hq * 32 + e0 + 8], w3 = ew[hq * 32 + e0 + 12];
            float4 x0 = ldh4(A.xsrc, s0 * 16 + q);
            float4 x1 = ldh4(A.xsrc, s1 * 16 + q);
            float4 x2 = ldh4(A.xsrc, s2 * 16 + q);
            float4 x3 = ldh4(A.xsrc, s3 * 16 + q);
            acc.x = fmaf(w0, x0.x, acc.x); acc.y = fmaf(w0, x0.y, acc.y);
            acc.z = fmaf(w0, x0.z, acc.z); acc.w = fmaf(w0, x0.w, acc.w);
            acc.x = fmaf(w1, x1.x, acc.x); acc.y = fmaf(w1, x1.y, acc.y);
            acc.z = fmaf(w1, x1.z, acc.z); acc.w = fmaf(w1, x1.w, acc.w);
            acc.x = fmaf(w2, x2.x, acc.x); acc.y = fmaf(w2, x2.y, acc.y);
            acc.z = fmaf(w2, x2.z, acc.z); acc.w = fmaf(w2, x2.w, acc.w);
            acc.x = fmaf(w3, x3.x, acc.x); acc.y = fmaf(w3, x3.y, acc.y);
            acc.z = fmaf(w3, x3.z, acc.z); acc.w = fmaf(w3, x3.w, acc.w);
        }
        for (; it < iters; it++) {
            int e0 = it * 4 + g;
            int s0 = es[e0];
            float w0 = ew[hq * 32 + e0];
            float4 x0 = ldh4(A.xsrc, s0 * 16 + q);
            acc.x = fmaf(w0, x0.x, acc.x); acc.y = fmaf(w0, x0.y, acc.y);
            acc.z = fmaf(w0, x0.z, acc.z); acc.w = fmaf(w0, x0.w, acc.w);
        }
    }
    acc.x += __shfl_xor(acc.x, 16);
    acc.y += __shfl_xor(acc.y, 16);
    acc.z += __shfl_xor(acc.z, 16);
    acc.w += __shfl_xor(acc.w, 16);
    acc.x += __shfl_xor(acc.x, 32);
    acc.y += __shfl_xor(acc.y, 32);
    acc.z += __shfl_xor(acc.z, 32);
    acc.w += __shfl_xor(acc.w, 32);
    float dtot = halfred(den);
    float dq = __shfl(dtot, (q >= 8) ? 32 : 0);
    if (g == 0) {
        float r = 1.f / (dq + 1e-16f);
        float4 o;
        o.x = fmaxf(acc.x * r, 0.f);
        o.y = fmaxf(acc.y * r, 0.f);
        o.z = fmaxf(acc.z * r, 0.f);
        o.w = fmaxf(acc.w * r, 0.f);
        *(float4*)&A.out[node * 64 + q * 4] = o;
    }
}

// ---------------------------------------------------------------------------
__global__ __launch_bounds__(256, 4) void kred2_kernel(
    const float* __restrict__ xin0, const float* __restrict__ xin1,
    const float* __restrict__ kw, const float* __restrict__ kb,
    float* __restrict__ kacc0, float* __restrict__ kacc1, int n)
{
    const float* xin = blockIdx.y ? xin1 : xin0;
    float* kacc = blockIdx.y ? kacc1 : kacc0;
    __shared__ __align__(16) float xs[16][64];
    __shared__ float red[256];
    int tid = threadIdx.x, lane = tid & 63, wid = tid >> 6;
    float Wreg[64];
#pragma unroll
    for (int k = 0; k < 64; k++) Wreg[k] = kw[k * 64 + lane];
    float bc = kb[lane];
    int qn = tid >> 4, qq = tid & 15;
    float kl = 0.f;
    for (int base = blockIdx.x * 16; base < n; base += gridDim.x * 16) {
        __syncthreads();
        int node = base + qn;
        if (node < n) *(float4*)&xs[qn][qq * 4] = ld4(xin, node * 16 + qq);
        __syncthreads();
#pragma unroll
        for (int nd = 0; nd < 4; nd++) {
            int nc = base + wid * 4 + nd;
            if (nc >= n) break;
            float acc = bc;
#pragma unroll
            for (int k4 = 0; k4 < 16; k4++) {
                float4 xv = *(const float4*)&xs[wid * 4 + nd][k4 * 4];
                acc = fmaf(xv.x, Wreg[4 * k4 + 0], acc);
                acc = fmaf(xv.y, Wreg[4 * k4 + 1], acc);
                acc = fmaf(xv.z, Wreg[4 * k4 + 2], acc);
                acc = fmaf(xv.w, Wreg[4 * k4 + 3], acc);
            }
            kl += tanhf(acc);
        }
    }
    red[tid] = kl;
    __syncthreads();
    if (wid == 0) {
        float s = red[lane] + red[64 + lane] + red[128 + lane] + red[192 + lane];
        atomicAdd(&kacc[lane], s);
    }
}

// ---------------------------------------------------------------------------
__global__ __launch_bounds__(256, 4) void final_kernel(
    const float* __restrict__ t0, const float* __restrict__ t1,
    const float* __restrict__ kacc, const float* __restrict__ qsem, float inv_n,
    const float* __restrict__ xm,
    const float* __restrict__ w0, const float* __restrict__ b0,
    const float* __restrict__ w1, const float* __restrict__ b1,
    const float* __restrict__ wv,
    float* __restrict__ action, float* __restrict__ vsum, int n)
{
    __shared__ __align__(16) float xs[16][64];
    __shared__ __align__(16) float hs[4][4][68];
    __shared__ float W1s[1024];
    __shared__ float red[256];
    int tid = threadIdx.x, lane = tid & 63, wid = tid >> 6;
    int qn = tid >> 4, qq = tid & 15;
    float W0reg[64];
#pragma unroll
    for (int k = 0; k < 64; k++) W0reg[k] = w0[k * 64 + lane];
    float b0c = b0[lane], b1c = b1[lane & 15];
    float2 at = sem_attn(kacc, qsem, inv_n, lane);
    float ca0 = at.x, ca1 = at.y;
    float4 wvq = ld4(wv, qq);
    for (int i = tid; i < 1024; i += 256) W1s[i] = w1[i];
    float vloc = 0.f;
    int n2 = 2 * n;
    for (int base = blockIdx.x * 16; base < n2; base += gridDim.x * 16) {
        __syncthreads();
        int node = base + qn;
        if (node < n2) {
            float4 xq;
            if (node < n) {
                float4 u = ld4(t0, node * 16 + qq), v = ld4(t1, node * 16 + qq);
                xq.x = ca0 * u.x + ca1 * v.x; xq.y = ca0 * u.y + ca1 * v.y;
                xq.z = ca0 * u.z + ca1 * v.z; xq.w = ca0 * u.w + ca1 * v.w;
            } else {
                xq = ld4(xm, (node - n) * 16 + qq);
            }
            *(float4*)&xs[qn][qq * 4] = xq;
            vloc += xq.x * wvq.x + xq.y * wvq.y + xq.z * wvq.z + xq.w * wvq.w;
        }
        __syncthreads();
#pragma unroll
        for (int nd = 0; nd < 4; nd++) {
            int nc = base + wid * 4 + nd;
            if (nc >= n2) break;
            float acc = b0c;
#pragma unroll
            for (int k4 = 0; k4 < 16; k4++) {
                float4 xv = *(const float4*)&xs[wid * 4 + nd][k4 * 4];
                acc = fmaf(xv.x, W0reg[4 * k4 + 0], acc);
                acc = fmaf(xv.y, W0reg[4 * k4 + 1], acc);
                acc = fmaf(xv.z, W0reg[4 * k4 + 2], acc);
                acc = fmaf(xv.w, W0reg[4 * k4 + 3], acc);
            }
            hs[wid][nd][lane] = acc;
        }
        __syncthreads();
        int nd2 = lane >> 4, c2 = lane & 15;
        int nc2 = base + wid * 4 + nd2;
        if (nc2 < n2) {
            float acc2 = b1c;
#pragma unroll
            for (int k4 = 0; k4 < 16; k4++) {
                float4 hv = *(const float4*)&hs[wid][nd2][k4 * 4];
                acc2 = fmaf(hv.x, W1s[(4 * k4 + 0) * 16 + c2], acc2);
                acc2 = fmaf(hv.y, W1s[(4 * k4 + 1) * 16 + c2], acc2);
                acc2 = fmaf(hv.z, W1s[(4 * k4 + 2) * 16 + c2], acc2);
                acc2 = fmaf(hv.w, W1s[(4 * k4 + 3) * 16 + c2], acc2);
            }
            action[(size_t)nc2 * 16 + c2] = tanhf(acc2);
        }
    }
    red[tid] = vloc;
    __syncthreads();
    for (int s = 128; s; s >>= 1) {
        if (tid < s) red[tid] += red[tid + s];
        __syncthreads();
    }
    if (tid == 0) atomicAdd(vsum, red[0]);
}

__global__ void value_finish_kernel(const float* __restrict__ vsum,
                                    const float* __restrict__ vb,
                                    float* __restrict__ out, int twoN)
{
    if (threadIdx.x == 0 && blockIdx.x == 0)
        out[0] = vsum[0] / (float)twoN + vb[0];
}

extern "C" void kernel_launch(void* const* d_in, const int* in_sizes, int n_in,
                              void* d_out, int out_size, void* d_ws, size_t ws_size,
                              hipStream_t stream)
{
    const int N = in_sizes[0] / 16;
    const int E = in_sizes[2] / 2;
    const int NB = (N + BUCKET_NODES - 1) / BUCKET_NODES;

    auto f = [&](int i) { return (const float*)d_in[i]; };
    const float* x_job = f(0);
    const float* x_mac = f(1);
    const int* ei_jm = (const int*)d_in[2];
    const int* ei_mj = (const int*)d_in[3];
    const int* ei_jj = (const int*)d_in[4];
    const float* enc_wj = f(5);
    const float* enc_bj = f(6);
    const float* enc_wm = f(7);
    const float* enc_bm = f(8);
    const float* proj_w = f(9);
    const float* proj_b = f(10);
    const float* att_src = f(11);
    const float* att_dst = f(12);
    const float* klin_w = f(13);
    const float* klin_b = f(14);
    const float* q_sem = f(15);
    const float* lin0_w = f(16);
    const float* lin0_b = f(17);
    const float* lout_w = f(18);
    const float* lout_b = f(19);
    const float* linv_w = f(20);
    const float* linv_b = f(21);

    float* action = (float*)d_out;
    float* value_out = action + (size_t)2 * N * 16;

    char* base = (char*)d_ws;
    size_t off = 0;
    auto alloc = [&](size_t bytes) -> void* {
        void* p = base + off;
        off += (bytes + 255) & ~(size_t)255;
        return p;
    };
    int* cursor3 = (int*)alloc((size_t)3 * NB * 4);
    float* kacc = (float*)alloc(256 * 4);
    float* vsum = (float*)alloc(4);
    size_t zero_bytes = off;

    int* rowptr3 = (int*)alloc((size_t)3 * N * 4);
    int* rowend3 = (int*)alloc((size_t)3 * N * 4);
    int* colsrc3 = (int*)alloc((size_t)3 * E * 4);
    int* binned3 = (int*)alloc((size_t)3 * NB * BUCKET_CAP * 4);
    __half* pj = (__half*)alloc((size_t)N * 64 * 2);
    __half* pm = (__half*)alloc((size_t)N * 64 * 2);
    float* out_jm0 = (float*)alloc((size_t)N * 64 * 4);
    float* out_jm1 = (float*)alloc((size_t)N * 64 * 4);
    float* out_mj = (float*)alloc((size_t)N * 64 * 4);
    float* out_jj = (float*)alloc((size_t)N * 64 * 4);
    float* as_jm = (float*)alloc((size_t)N * 2 * 4);
    float* ad_jm = (float*)alloc((size_t)N * 2 * 4);
    float* as_mj = (float*)alloc((size_t)N * 2 * 4);
    float* ad_mj = (float*)alloc((size_t)N * 2 * 4);
    float* as_jj = (float*)alloc((size_t)N * 2 * 4);
    float* ad_jj = (float*)alloc((size_t)N * 2 * 4);

    hipMemsetAsync(d_ws, 0, zero_bytes, stream);

    dim3 blk(256);

    const int* rp0 = rowptr3;
    const int* rp1 = rowptr3 + N;
    const int* rp2 = rowptr3 + 2 * N;
    const int* re0 = rowend3;
    const int* re1 = rowend3 + N;
    const int* re2 = rowend3 + 2 * N;
    const int* cs0 = colsrc3;
    const int* cs1 = colsrc3 + E;
    const int* cs2 = colsrc3 + 2 * E;

    int ab = (N + 3) / 4;
    int binb = (E + BIN_CHUNK - 1) / BIN_CHUNK;
    float* out_jm_l[2] = {out_jm0, out_jm1};
    float inv_n = 1.f / (float)N;

    for (int l = 0; l < 2; l++) {
        const float* pwj = proj_w + (size_t)(l * 2 + 0) * 4096;
        const float* pwm = proj_w + (size_t)(l * 2 + 1) * 4096;
        const float* pbj = proj_b + (l * 2 + 0) * 64;
        const float* pbm = proj_b + (l * 2 + 1) * 64;
        const float* as0 = att_src + (l * 3 + 0) * 64;
        const float* as1 = att_src + (l * 3 + 1) * 64;
        const float* as2 = att_src + (l * 3 + 2) * 64;
        const float* ad0 = att_dst + (l * 3 + 0) * 64;
        const float* ad1 = att_dst + (l * 3 + 1) * 64;
        const float* ad2 = att_dst + (l * 3 + 2) * 64;

        if (l == 0) {
            EncSide ja = {x_job, enc_wj, enc_bj, pwj, pbj, pj,
                          as0, as_jm, ad1, ad_mj, as2, as_jj, ad2, ad_jj};
            EncSide ma = {x_mac, enc_wm, enc_bm, pwm, pbm, pm,
                          ad0, ad_jm, as1, as_mj, nullptr, nullptr, nullptr, nullptr};
            phase1_kernel<<<3 * binb + 2 * ENCB, blk, 0, stream>>>(
                ja, ma, N, ei_jm, ei_mj, ei_jj, ei_jm + E, ei_mj + E, ei_jj + E,
                cursor3, binned3, E, NB, binb);
            bucket_kernel<<<dim3(NB, 3), blk, 0, stream>>>(
                cursor3, binned3, rowptr3, rowend3, colsrc3, N, NB, E);
        } else {
            ProjSide ja = {out_mj, out_jj, kacc, q_sem, inv_n, pwj, pbj, pj,
                           as0, as_jm, ad1, ad_mj, as2, as_jj, ad2, ad_jj};
            ProjSide ma = {out_jm0, nullptr, nullptr, nullptr, 0.f, pwm, pbm, pm,
                           ad0, ad_jm, as1, as_mj, nullptr, nullptr, nullptr, nullptr};
            proj2_kernel<<<dim3(GEMM_GRID, 2), blk, 0, stream>>>(ja, ma, N);
        }

        AggSide A0 = {rp0, re0, cs0, pj, as_jm, ad_jm, out_jm_l[l]};
        AggSide A1 = {rp1, re1, cs1, pm, as_mj, ad_mj, out_mj};
        AggSide A2 = {rp2, re2, cs2, pj, as_jj, ad_jj, out_jj};
        agg3_kernel<<<dim3(ab, 3), blk, 0, stream>>>(A0, A1, A2, N);

        const float* kw = klin_w + (size_t)l * 4096;
        const float* kb = klin_b + l * 64;
        float* k0 = kacc + l * 128;
        float* k1 = k0 + 64;
        kred2_kernel<<<dim3(KRED_GRID, 2), blk, 0, stream>>>(out_mj, out_jj, kw, kb, k0, k1, N);
    }

    final_kernel<<<FINALB, blk, 0, stream>>>(out_mj, out_jj,
                                             kacc + 128, q_sem + 64, inv_n,
                                             out_jm1,
                                             lin0_w, lin0_b, lout_w, lout_b, linv_w,
                                             action, vsum, N);
    value_finish_kernel<<<1, 64, 0, stream>>>(vsum, linv_b, value_out, 2 * N);
}